// Round 1
// baseline (312.609 us; speedup 1.0000x reference)
//
#include <hip/hip_runtime.h>
#include <math.h>

#define T_TOK 2048
#define H_DIM 2048
#define V_DIM 32000
#define NE    16

// ---------------------------------------------------------------------------
// Kernel 1: gating. One block (256 thr) per token.
//  - 16 per-thread dot accumulators over H, wave shuffle-reduce, LDS combine
//  - thread 0: softmax(16), top-2 (jax tie-break: lowest index), renormalize
//  - params[t] = (w0, w1, bits(i0), bits(i1))
//  - threads 0..15: atomicAdd softmax score into usage[e]
// ---------------------------------------------------------------------------
__global__ __launch_bounds__(256) void gate_kernel(const float* __restrict__ hs,
                                                   const float* __restrict__ gw,
                                                   float* __restrict__ usage,
                                                   float4* __restrict__ params)
{
    const int t   = blockIdx.x;
    const int tid = threadIdx.x;

    float acc[NE];
#pragma unroll
    for (int e = 0; e < NE; ++e) acc[e] = 0.f;

    const float* hrow = hs + (size_t)t * H_DIM;
#pragma unroll
    for (int i = tid; i < H_DIM; i += 256) {
        float x = hrow[i];
#pragma unroll
        for (int e = 0; e < NE; ++e) acc[e] += x * gw[e * H_DIM + i];
    }

    // wave (64-lane) shuffle reduction of each accumulator
#pragma unroll
    for (int e = 0; e < NE; ++e) {
        float v = acc[e];
#pragma unroll
        for (int off = 32; off > 0; off >>= 1) v += __shfl_down(v, off, 64);
        acc[e] = v;
    }

    __shared__ float partial[4][NE];
    __shared__ float logits[NE];
    __shared__ float exps[NE + 1];   // [NE] holds the softmax denominator

    const int wave = tid >> 6, lane = tid & 63;
    if (lane == 0) {
#pragma unroll
        for (int e = 0; e < NE; ++e) partial[wave][e] = acc[e];
    }
    __syncthreads();

    if (tid < NE)
        logits[tid] = partial[0][tid] + partial[1][tid] + partial[2][tid] + partial[3][tid];
    __syncthreads();

    if (tid == 0) {
        float m = logits[0];
#pragma unroll
        for (int e = 1; e < NE; ++e) m = fmaxf(m, logits[e]);
        float Z = 0.f;
#pragma unroll
        for (int e = 0; e < NE; ++e) { float ex = expf(logits[e] - m); exps[e] = ex; Z += ex; }
        exps[NE] = Z;

        // top-2, strict > ascending scan => lowest index wins ties (jax semantics)
        int i0 = 0; float l0 = logits[0];
#pragma unroll
        for (int e = 1; e < NE; ++e) if (logits[e] > l0) { l0 = logits[e]; i0 = e; }
        int i1 = -1; float l1 = -INFINITY;
#pragma unroll
        for (int e = 0; e < NE; ++e) if (e != i0 && logits[e] > l1) { l1 = logits[e]; i1 = e; }

        float e0 = exps[i0], e1 = exps[i1];
        float inv = 1.f / (e0 + e1);
        params[t] = make_float4(e0 * inv, e1 * inv, __int_as_float(i0), __int_as_float(i1));
    }
    __syncthreads();

    if (tid < NE)
        atomicAdd(usage + tid, exps[tid] / exps[NE]);
}

// ---------------------------------------------------------------------------
// Kernel 2: bias = w0*eb[i0,:] + w1*eb[i1,:], float4-vectorized, flat index.
// 2048*8000 float4 elements = 64000 blocks x 256 threads (exact).
// ---------------------------------------------------------------------------
__global__ __launch_bounds__(256) void bias_kernel(const float4* __restrict__ eb,
                                                   const float4* __restrict__ params,
                                                   float4* __restrict__ out)
{
    const int V4 = V_DIM / 4;                       // 8000
    unsigned int n = blockIdx.x * 256u + threadIdx.x;  // < 16,384,000
    int t = (int)(n / (unsigned)V4);
    int v = (int)(n % (unsigned)V4);

    float4 p = params[t];
    int i0 = __float_as_int(p.z), i1 = __float_as_int(p.w);

    float4 a = eb[(size_t)i0 * V4 + v];
    float4 b = eb[(size_t)i1 * V4 + v];
    float4 r;
    r.x = p.x * a.x + p.y * b.x;
    r.y = p.x * a.y + p.y * b.y;
    r.z = p.x * a.z + p.y * b.z;
    r.w = p.x * a.w + p.y * b.w;
    out[n] = r;
}

// ---------------------------------------------------------------------------
// Kernel 3: aux_loss = NE * sum_e (u_e * log u_e), u_e = usage_e / T
// ---------------------------------------------------------------------------
__global__ void aux_kernel(const float* __restrict__ usage, float* __restrict__ out)
{
    int tid = threadIdx.x;  // 64 threads, one wave
    float v = 0.f;
    if (tid < NE) {
        float u = usage[tid] / (float)T_TOK;
        v = u * logf(u);
    }
#pragma unroll
    for (int off = 8; off > 0; off >>= 1) v += __shfl_down(v, off, 64);
    if (tid == 0) out[0] = v * (float)NE;
}

extern "C" void kernel_launch(void* const* d_in, const int* in_sizes, int n_in,
                              void* d_out, int out_size, void* d_ws, size_t ws_size,
                              hipStream_t stream)
{
    const float* hs = (const float*)d_in[0];   // (T, H)
    const float* gw = (const float*)d_in[1];   // (E, H)
    const float* eb = (const float*)d_in[2];   // (E, V)
    float* out = (float*)d_out;                // T*V floats then 1 aux float

    float*  usage  = (float*)d_ws;                       // 16 floats
    float4* params = (float4*)((char*)d_ws + 256);       // T float4s

    // d_ws is re-poisoned before every launch: zero the usage accumulators
    hipMemsetAsync(d_ws, 0, 256, stream);

    gate_kernel<<<T_TOK, 256, 0, stream>>>(hs, gw, usage, params);

    const unsigned total4 = (unsigned)T_TOK * (V_DIM / 4);     // 16,384,000
    bias_kernel<<<total4 / 256, 256, 0, stream>>>((const float4*)eb, params, (float4*)out);

    aux_kernel<<<1, 64, 0, stream>>>(usage, out + (size_t)T_TOK * V_DIM);
}

// Round 3
// 294.119 us; speedup vs baseline: 1.0629x; 1.0629x over previous
//
#include <hip/hip_runtime.h>
#include <math.h>

#define T_TOK 2048
#define H_DIM 2048
#define V_DIM 32000
#define NE    16

typedef float fvec4 __attribute__((ext_vector_type(4)));

// ws layout:
//   scores: NE * T_TOK floats (transposed: scores[e*T_TOK + t])  = 128 KB
//   params: T_TOK float4s, offset 128 KB                          = 32 KB
#define WS_SCORES(ws)  ((float*)(ws))
#define WS_PARAMS(ws)  ((float4*)((char*)(ws) + NE * T_TOK * sizeof(float)))

// ---------------------------------------------------------------------------
// Kernel 1: gating. One block (256 thr) per token. float4 dot products,
// wave shuffle-reduce, LDS combine. No atomics: per-token softmax probs are
// written transposed to scores[e][t]; a tiny reduce kernel does usage/aux.
// ---------------------------------------------------------------------------
__global__ __launch_bounds__(256) void gate_kernel(const float4* __restrict__ hs,
                                                   const float4* __restrict__ gw,
                                                   float* __restrict__ scores,
                                                   float4* __restrict__ params)
{
    const int t   = blockIdx.x;
    const int tid = threadIdx.x;
    const int H4  = H_DIM / 4;   // 512

    float acc[NE];
#pragma unroll
    for (int e = 0; e < NE; ++e) acc[e] = 0.f;

    const float4* hrow = hs + (size_t)t * H4;
#pragma unroll
    for (int i = tid; i < H4; i += 256) {     // 2 iterations
        float4 x = hrow[i];
#pragma unroll
        for (int e = 0; e < NE; ++e) {
            float4 g = gw[e * H4 + i];
            acc[e] += x.x * g.x + x.y * g.y + x.z * g.z + x.w * g.w;
        }
    }

    // 64-lane shuffle reduction per accumulator
#pragma unroll
    for (int e = 0; e < NE; ++e) {
        float v = acc[e];
#pragma unroll
        for (int off = 32; off > 0; off >>= 1) v += __shfl_down(v, off, 64);
        acc[e] = v;
    }

    __shared__ float partial[4][NE];
    __shared__ float exps[NE + 1];   // [NE] = softmax denominator

    const int wave = tid >> 6, lane = tid & 63;
    if (lane == 0) {
#pragma unroll
        for (int e = 0; e < NE; ++e) partial[wave][e] = acc[e];
    }
    __syncthreads();

    if (tid == 0) {
        float logits[NE];
        float m = -INFINITY;
#pragma unroll
        for (int e = 0; e < NE; ++e) {
            logits[e] = partial[0][e] + partial[1][e] + partial[2][e] + partial[3][e];
            m = fmaxf(m, logits[e]);
        }
        float Z = 0.f;
#pragma unroll
        for (int e = 0; e < NE; ++e) { float ex = expf(logits[e] - m); exps[e] = ex; Z += ex; }
        exps[NE] = Z;

        // top-2, strict > ascending scan => lowest index wins ties (jax semantics)
        int i0 = 0; float l0 = logits[0];
#pragma unroll
        for (int e = 1; e < NE; ++e) if (logits[e] > l0) { l0 = logits[e]; i0 = e; }
        int i1 = -1; float l1 = -INFINITY;
#pragma unroll
        for (int e = 0; e < NE; ++e) if (e != i0 && logits[e] > l1) { l1 = logits[e]; i1 = e; }

        float e0 = exps[i0], e1 = exps[i1];
        float inv = 1.f / (e0 + e1);
        params[t] = make_float4(e0 * inv, e1 * inv, __int_as_float(i0), __int_as_float(i1));
    }
    __syncthreads();

    if (tid < NE)
        scores[tid * T_TOK + t] = exps[tid] / exps[NE];
}

// ---------------------------------------------------------------------------
// Kernel 2: bias = w0*eb[i0,:] + w1*eb[i1,:], float4-vectorized, flat index.
// Non-temporal stores keep the 262 MB write stream out of L2 so the 2 MB
// expert_biases working set stays resident.
// ---------------------------------------------------------------------------
__global__ __launch_bounds__(256) void bias_kernel(const float4* __restrict__ eb,
                                                   const float4* __restrict__ params,
                                                   float4* __restrict__ out)
{
    const int V4 = V_DIM / 4;                          // 8000
    unsigned int n = blockIdx.x * 256u + threadIdx.x;  // < 16,384,000
    int t = (int)(n / (unsigned)V4);
    int v = (int)(n % (unsigned)V4);

    float4 p = params[t];
    int i0 = __float_as_int(p.z), i1 = __float_as_int(p.w);

    float4 a = eb[(size_t)i0 * V4 + v];
    float4 b = eb[(size_t)i1 * V4 + v];
    fvec4 r;
    r.x = p.x * a.x + p.y * b.x;
    r.y = p.x * a.y + p.y * b.y;
    r.z = p.x * a.z + p.y * b.z;
    r.w = p.x * a.w + p.y * b.w;
    __builtin_nontemporal_store(r, (fvec4*)out + n);
}

// ---------------------------------------------------------------------------
// Kernel 3: usage + aux loss. One block, 16 waves; wave e reduces the
// contiguous row scores[e][0..T). aux = NE * sum_e u_e*log(u_e), u_e = mean.
// ---------------------------------------------------------------------------
__global__ __launch_bounds__(1024) void aux_kernel(const float* __restrict__ scores,
                                                   float* __restrict__ out)
{
    const int e    = threadIdx.x >> 6;   // wave id = expert
    const int lane = threadIdx.x & 63;

    float s = 0.f;
    const float* row = scores + e * T_TOK;
#pragma unroll
    for (int i = lane; i < T_TOK; i += 64) s += row[i];   // 32 iterations
#pragma unroll
    for (int off = 32; off > 0; off >>= 1) s += __shfl_down(s, off, 64);

    __shared__ float u[NE];
    if (lane == 0) u[e] = s;
    __syncthreads();

    if (threadIdx.x == 0) {
        float aux = 0.f;
#pragma unroll
        for (int i = 0; i < NE; ++i) {
            float ui = u[i] / (float)T_TOK;
            aux += ui * logf(ui);
        }
        out[0] = aux * (float)NE;
    }
}

extern "C" void kernel_launch(void* const* d_in, const int* in_sizes, int n_in,
                              void* d_out, int out_size, void* d_ws, size_t ws_size,
                              hipStream_t stream)
{
    const float* hs = (const float*)d_in[0];   // (T, H)
    const float* gw = (const float*)d_in[1];   // (E, H)
    const float* eb = (const float*)d_in[2];   // (E, V)
    float* out = (float*)d_out;                // T*V floats then 1 aux float

    float*  scores = WS_SCORES(d_ws);
    float4* params = WS_PARAMS(d_ws);

    gate_kernel<<<T_TOK, 256, 0, stream>>>((const float4*)hs, (const float4*)gw,
                                           scores, params);

    const unsigned total4 = (unsigned)T_TOK * (V_DIM / 4);     // 16,384,000
    bias_kernel<<<total4 / 256, 256, 0, stream>>>((const float4*)eb, params, (float4*)out);

    aux_kernel<<<1, 1024, 0, stream>>>(scores, out + (size_t)T_TOK * V_DIM);
}